// Round 1
// baseline (273.198 us; speedup 1.0000x reference)
//
#include <hip/hip_runtime.h>
#include <math.h>

// Problem constants
#define NN    8
#define C1    256
#define CC    256     // c
#define HH    64
#define WW    64
#define HW    4096
#define NHW   32768
#define OMC   112     // padded offset-mask channels
#define DALL  368     // 256 (value) + 112 (om)
#define GG    4
#define KPn   9
#define GC    64

// Workspace layout (floats):
//  Wall  [368*256]  @ 0
//  ball  [368]      @ 94208
//  Wout  [256*256]  @ 94576
//  bout  [256]      @ 160112
//  value [NHW*256]  @ 160512
//  om    [NHW*112]  @ 8549120
//  y     [NHW*256]  @ 12219136
//  total 20607744 floats = 82.4 MB

// ---------------- prep: fold weights ----------------
// Wall rows 0..255  : Wv  = value_w @ cv1_w
// Wall rows 256..367: Wom = om_w . diag(dw_w) @ cv1_w
// Wout = diag(s) (cv2_w @ out_w), s = gamma*rsqrt(var+eps)
// ball = [value_w@cv1_b + value_b ; om_w@(dw_w*cv1_b+dw_b)+om_b]
// bout = beta - mean*s
__global__ __launch_bounds__(256)
void prep_kernel(const float* __restrict__ cv1_w, const float* __restrict__ cv1_b,
                 const float* __restrict__ value_w, const float* __restrict__ value_b,
                 const float* __restrict__ dw_w, const float* __restrict__ dw_b,
                 const float* __restrict__ om_w, const float* __restrict__ om_b,
                 const float* __restrict__ out_w, const float* __restrict__ cv2_w,
                 const float* __restrict__ bn_g, const float* __restrict__ bn_b,
                 const float* __restrict__ bn_m, const float* __restrict__ bn_v,
                 float* __restrict__ Wall, float* __restrict__ ball,
                 float* __restrict__ Wout, float* __restrict__ bout)
{
    int job = blockIdx.x * 256 + threadIdx.x;
    if (job < 65536) {                       // Wv
        int d = job >> 8, cc = job & 255;
        float s = 0.f;
        for (int e = 0; e < 256; ++e)
            s = fmaf(value_w[d*256+e], cv1_w[e*256+cc], s);
        Wall[job] = s;
    } else if (job < 94208) {                // Wom
        int idx = job - 65536;
        int o = idx >> 8, cc = idx & 255;
        float s = 0.f;
        for (int e = 0; e < 256; ++e)
            s = fmaf(om_w[o*256+e]*dw_w[e], cv1_w[e*256+cc], s);
        Wall[65536 + idx] = s;
    } else if (job < 159744) {               // Wout
        int idx = job - 94208;
        int d = idx >> 8;
        float s = 0.f;
        for (int e = 0; e < 256; ++e)
            s = fmaf(cv2_w[d*256+e], out_w[e*256 + (idx & 255)], s);
        float sc = bn_g[d] * rsqrtf(bn_v[d] + 1e-5f);
        Wout[idx] = s * sc;
    } else if (job < 160000) {               // bv
        int d = job - 159744;
        float s = value_b[d];
        for (int e = 0; e < 256; ++e) s = fmaf(value_w[d*256+e], cv1_b[e], s);
        ball[d] = s;
    } else if (job < 160112) {               // bom
        int o = job - 160000;
        float s = om_b[o];
        for (int e = 0; e < 256; ++e)
            s = fmaf(om_w[o*256+e], fmaf(dw_w[e], cv1_b[e], dw_b[e]), s);
        ball[256 + o] = s;
    } else if (job < 160368) {               // bout
        int d = job - 160112;
        float sc = bn_g[d] * rsqrtf(bn_v[d] + 1e-5f);
        bout[d] = fmaf(-bn_m[d], sc, bn_b[d]);
    }
}

// ---------------- GEMM1: [value|om] = x @ Wallᵀ + ball ----------------
// x is NCHW: for a pixel tile, channel k row is 64 contiguous floats (coalesced).
// 64 pixels x 64 outputs per block, BK=16, 4x4 per thread, float4 LDS reads.
__global__ __launch_bounds__(256)
void gemm_vo_kernel(const float* __restrict__ x, const float* __restrict__ Wall,
                    const float* __restrict__ ball,
                    float* __restrict__ value, float* __restrict__ om)
{
    __shared__ float Xs[16][64];    // [k][pixel]
    __shared__ float Ws2[16][68];   // [k][d]  (transposed on store; 68-pad)
    int p0 = blockIdx.x * 64;
    int d0 = blockIdx.y * 64;
    int n   = p0 >> 12;
    int hw0 = p0 & 4095;
    int t = threadIdx.x;
    const float* xbase = x + (size_t)n * C1 * HW + hw0;

    float acc[4][4] = {};
    int px = (t & 15) << 2;   // pixel quad
    int dx = (t >> 4) << 2;   // output quad

    for (int c0 = 0; c0 < 256; c0 += 16) {
        #pragma unroll
        for (int it = 0; it < 4; ++it) {
            int idx = t + it * 256;
            int kk = idx >> 6, pp = idx & 63;
            Xs[kk][pp] = xbase[(size_t)(c0 + kk) * HW + pp];
        }
        #pragma unroll
        for (int it = 0; it < 4; ++it) {
            int idx = t + it * 256;
            int dd = idx >> 4, kk = idx & 15;
            int d = d0 + dd;
            Ws2[kk][dd] = (d < DALL) ? Wall[(size_t)d * 256 + c0 + kk] : 0.f;
        }
        __syncthreads();
        #pragma unroll
        for (int kk = 0; kk < 16; ++kk) {
            float4 a = *reinterpret_cast<const float4*>(&Xs[kk][px]);
            float4 b = *reinterpret_cast<const float4*>(&Ws2[kk][dx]);
            float av[4] = {a.x, a.y, a.z, a.w};
            float bv[4] = {b.x, b.y, b.z, b.w};
            #pragma unroll
            for (int i = 0; i < 4; ++i)
                #pragma unroll
                for (int j = 0; j < 4; ++j)
                    acc[i][j] = fmaf(av[i], bv[j], acc[i][j]);
        }
        __syncthreads();
    }

    int dq = d0 + dx;
    if (dq >= DALL) return;
    float4 bb = *reinterpret_cast<const float4*>(&ball[dq]);
    float bvv[4] = {bb.x, bb.y, bb.z, bb.w};
    #pragma unroll
    for (int i = 0; i < 4; ++i) {
        int p = p0 + px + i;
        float4 v;
        v.x = acc[i][0] + bvv[0];
        v.y = acc[i][1] + bvv[1];
        v.z = acc[i][2] + bvv[2];
        v.w = acc[i][3] + bvv[3];
        if (dq < 256)
            *reinterpret_cast<float4*>(&value[(size_t)p * 256 + dq]) = v;
        else
            *reinterpret_cast<float4*>(&om[(size_t)p * 112 + (dq - 256)]) = v;
    }
}

// ---------------- DCNv4 core ----------------
// One block per pixel; wave g handles group g; lane = channel within group.
__global__ __launch_bounds__(256)
void dcn_kernel(const float* __restrict__ value, const float* __restrict__ om,
                float* __restrict__ y)
{
    int p = blockIdx.x;
    int t = threadIdx.x;
    int g = t >> 6;
    int lane = t & 63;
    __shared__ float om_s[108];
    if (t < 108) om_s[t] = om[(size_t)p * 112 + t];
    __syncthreads();

    int n = p >> 12;
    int hw = p & 4095;
    int h = hw >> 6, w = hw & 63;
    const float* vbase = value + ((size_t)n * HW) * 256 + g * 64 + lane;
    const float* o = om_s + g * 27;

    float acc = 0.f;
    #pragma unroll
    for (int k = 0; k < 9; ++k) {
        float dxo = o[2*k], dyo = o[2*k+1], m = o[18+k];
        float pxf = (float)(w + (k % 3) - 1) + dxo;
        float pyf = (float)(h + (k / 3) - 1) + dyo;
        float x0f = floorf(pxf), y0f = floorf(pyf);
        float fx = pxf - x0f, fy = pyf - y0f;
        int x0 = (int)x0f, y0 = (int)y0f;
        float s = 0.f;
        #pragma unroll
        for (int dyy = 0; dyy < 2; ++dyy) {
            #pragma unroll
            for (int dxx = 0; dxx < 2; ++dxx) {
                int yy = y0 + dyy, xx = x0 + dxx;
                bool valid = (yy >= 0) & (yy < HH) & (xx >= 0) & (xx < WW);
                float wgt = (dyy ? fy : 1.f - fy) * (dxx ? fx : 1.f - fx);
                int yc = min(max(yy, 0), HH - 1);
                int xc = min(max(xx, 0), WW - 1);
                float v = vbase[(size_t)(yc * WW + xc) * 256];
                s = fmaf(v, valid ? wgt : 0.f, s);
            }
        }
        acc = fmaf(m, s, acc);
    }
    y[(size_t)p * 256 + g * 64 + lane] = acc;
}

// ---------------- GEMM2 + BN/SiLU epilogue + NCHW store ----------------
__global__ __launch_bounds__(256)
void gemm_out_kernel(const float* __restrict__ yin, const float* __restrict__ Wout,
                     const float* __restrict__ bout, float* __restrict__ out)
{
    __shared__ float Ys2[16][68];   // [k][pixel]
    __shared__ float Ws2[16][68];   // [k][d]
    int p0 = blockIdx.x * 64;
    int d0 = blockIdx.y * 64;
    int n   = p0 >> 12;
    int hw0 = p0 & 4095;
    int t = threadIdx.x;

    float acc[4][4] = {};
    int px = (t & 15) << 2;
    int dx = (t >> 4) << 2;

    for (int c0 = 0; c0 < 256; c0 += 16) {
        #pragma unroll
        for (int it = 0; it < 4; ++it) {
            int idx = t + it * 256;
            int pp = idx >> 4, kk = idx & 15;
            Ys2[kk][pp] = yin[(size_t)(p0 + pp) * 256 + c0 + kk];
            Ws2[kk][pp] = Wout[(size_t)(d0 + pp) * 256 + c0 + kk];
        }
        __syncthreads();
        #pragma unroll
        for (int kk = 0; kk < 16; ++kk) {
            float4 a = *reinterpret_cast<const float4*>(&Ys2[kk][px]);
            float4 b = *reinterpret_cast<const float4*>(&Ws2[kk][dx]);
            float av[4] = {a.x, a.y, a.z, a.w};
            float bv[4] = {b.x, b.y, b.z, b.w};
            #pragma unroll
            for (int i = 0; i < 4; ++i)
                #pragma unroll
                for (int j = 0; j < 4; ++j)
                    acc[i][j] = fmaf(av[i], bv[j], acc[i][j]);
        }
        __syncthreads();
    }

    #pragma unroll
    for (int j = 0; j < 4; ++j) {
        int d = d0 + dx + j;
        float bb = bout[d];
        float4 v;
        float z0 = acc[0][j] + bb; v.x = z0 / (1.f + expf(-z0));
        float z1 = acc[1][j] + bb; v.y = z1 / (1.f + expf(-z1));
        float z2 = acc[2][j] + bb; v.z = z2 / (1.f + expf(-z2));
        float z3 = acc[3][j] + bb; v.w = z3 / (1.f + expf(-z3));
        *reinterpret_cast<float4*>(&out[((size_t)n * 256 + d) * 4096 + hw0 + px]) = v;
    }
}

extern "C" void kernel_launch(void* const* d_in, const int* in_sizes, int n_in,
                              void* d_out, int out_size, void* d_ws, size_t ws_size,
                              hipStream_t stream) {
    const float* x       = (const float*)d_in[0];
    const float* cv1_w   = (const float*)d_in[1];
    const float* cv1_b   = (const float*)d_in[2];
    const float* value_w = (const float*)d_in[3];
    const float* value_b = (const float*)d_in[4];
    const float* dw_w    = (const float*)d_in[5];
    const float* dw_b    = (const float*)d_in[6];
    const float* om_w    = (const float*)d_in[7];
    const float* om_b    = (const float*)d_in[8];
    const float* out_w   = (const float*)d_in[9];
    const float* cv2_w   = (const float*)d_in[10];
    const float* bn_g    = (const float*)d_in[11];
    const float* bn_b    = (const float*)d_in[12];
    const float* bn_m    = (const float*)d_in[13];
    const float* bn_v    = (const float*)d_in[14];

    float* ws    = (float*)d_ws;
    float* Wall  = ws;
    float* ball  = ws + 94208;
    float* Wout  = ws + 94576;
    float* bout  = ws + 160112;
    float* value = ws + 160512;
    float* om    = ws + 8549120;
    float* y     = ws + 12219136;
    float* out   = (float*)d_out;

    prep_kernel<<<627, 256, 0, stream>>>(cv1_w, cv1_b, value_w, value_b, dw_w, dw_b,
                                         om_w, om_b, out_w, cv2_w,
                                         bn_g, bn_b, bn_m, bn_v,
                                         Wall, ball, Wout, bout);
    gemm_vo_kernel<<<dim3(512, 6), 256, 0, stream>>>(x, Wall, ball, value, om);
    dcn_kernel<<<32768, 256, 0, stream>>>(value, om, y);
    gemm_out_kernel<<<dim3(512, 4), 256, 0, stream>>>(y, Wout, bout, out);
}

// Round 2
// 154.776 us; speedup vs baseline: 1.7651x; 1.7651x over previous
//
#include <hip/hip_runtime.h>
#include <hip/hip_bf16.h>
#include <math.h>

#define NN    8
#define HH    64
#define WW    64
#define HW    4096
#define NHW   32768
#define DALL  384     // 256 value + 112 om + 16 pad
#define EPSBN 1e-5f

typedef __attribute__((ext_vector_type(8))) short short8v;
typedef __attribute__((ext_vector_type(4))) float f32x4;

__device__ __forceinline__ float b2f(unsigned short u) {
    union { unsigned int i; float f; } v; v.i = ((unsigned int)u) << 16; return v.f;
}
__device__ __forceinline__ unsigned short f2b(float f) {
    __hip_bfloat16 h = __float2bfloat16(f);
    return *reinterpret_cast<const unsigned short*>(&h);
}

// Workspace layout (bytes):
//  xt     [NHW][256] bf16  @ 0          (16777216)
//  VO     [NHW][384] bf16  @ 16777216   (25165824)
//  y      [NHW][256] bf16  @ 41943040   (16777216)
//  Wallbf [384][256] bf16  @ 58720256   (196608)
//  Woutbf [256][256] bf16  @ 58916864   (131072)
//  ball   [384] f32        @ 59047936   (1536)
//  bout   [256] f32        @ 59049472   (1024)

// ---------------- prep: fold weights (f32 math, bf16 weight output) ----------------
__global__ __launch_bounds__(256)
void prep_kernel(const float* __restrict__ cv1_w, const float* __restrict__ cv1_b,
                 const float* __restrict__ value_w, const float* __restrict__ value_b,
                 const float* __restrict__ dw_w, const float* __restrict__ dw_b,
                 const float* __restrict__ om_w, const float* __restrict__ om_b,
                 const float* __restrict__ out_w, const float* __restrict__ cv2_w,
                 const float* __restrict__ bn_g, const float* __restrict__ bn_b,
                 const float* __restrict__ bn_m, const float* __restrict__ bn_v,
                 unsigned short* __restrict__ Wallbf, float* __restrict__ ball,
                 unsigned short* __restrict__ Woutbf, float* __restrict__ bout)
{
    int job = blockIdx.x * 256 + threadIdx.x;
    if (job < 65536) {                          // Wv = value_w @ cv1_w
        int d = job >> 8, cc = job & 255;
        float s = 0.f;
        for (int e = 0; e < 256; ++e)
            s = fmaf(value_w[d*256+e], cv1_w[e*256+cc], s);
        Wallbf[job] = f2b(s);
    } else if (job < 94208) {                   // Wom = om_w.diag(dw_w) @ cv1_w
        int idx = job - 65536;
        int o = idx >> 8, cc = idx & 255;
        float s = 0.f;
        for (int e = 0; e < 256; ++e)
            s = fmaf(om_w[o*256+e]*dw_w[e], cv1_w[e*256+cc], s);
        Wallbf[job] = f2b(s);
    } else if (job < 98304) {                   // pad rows 368..383
        Wallbf[job] = 0;
    } else if (job < 163840) {                  // Wout = diag(s) cv2_w @ out_w
        int idx = job - 98304;
        int d = idx >> 8;
        float s = 0.f;
        for (int e = 0; e < 256; ++e)
            s = fmaf(cv2_w[d*256+e], out_w[e*256 + (idx & 255)], s);
        float sc = bn_g[d] * rsqrtf(bn_v[d] + EPSBN);
        Woutbf[idx] = f2b(s * sc);
    } else if (job < 164096) {                  // bv
        int d = job - 163840;
        float s = value_b[d];
        for (int e = 0; e < 256; ++e) s = fmaf(value_w[d*256+e], cv1_b[e], s);
        ball[d] = s;
    } else if (job < 164208) {                  // bom
        int o = job - 164096;
        float s = om_b[o];
        for (int e = 0; e < 256; ++e)
            s = fmaf(om_w[o*256+e], fmaf(dw_w[e], cv1_b[e], dw_b[e]), s);
        ball[256 + o] = s;
    } else if (job < 164224) {                  // ball pad
        ball[368 + job - 164208] = 0.f;
    } else if (job < 164480) {                  // bout
        int d = job - 164224;
        float sc = bn_g[d] * rsqrtf(bn_v[d] + EPSBN);
        bout[d] = fmaf(-bn_m[d], sc, bn_b[d]);
    }
}

// ---------------- cvt+transpose: x NCHW f32 -> xt [p][c] bf16 ----------------
__global__ __launch_bounds__(256)
void cvt_tr_kernel(const float* __restrict__ x, unsigned short* __restrict__ xt)
{
    __shared__ float Ls[64][65];
    int p0 = blockIdx.x * 64;
    int c0 = blockIdx.y * 64;
    int n = p0 >> 12, hw0 = p0 & 4095;
    int t = threadIdx.x;
    #pragma unroll
    for (int i = 0; i < 16; ++i) {
        int idx = t + i * 256;
        int cc = idx >> 6, pp = idx & 63;
        Ls[cc][pp] = x[((size_t)(n*256 + c0 + cc))*4096 + hw0 + pp];
    }
    __syncthreads();
    #pragma unroll
    for (int i = 0; i < 8; ++i) {
        int idx = t + i * 256;
        int pp = idx >> 5, cp = idx & 31;
        int c = cp * 2;
        ushort2 v;
        v.x = f2b(Ls[c][pp]);
        v.y = f2b(Ls[c+1][pp]);
        *reinterpret_cast<ushort2*>(&xt[(size_t)(p0 + pp)*256 + c0 + c]) = v;
    }
}

// ---------------- shared MFMA mainloop: 128x128 tile, BK=64, K=256 ----------------
// A rows = output rows (m), B rows = output cols (n); both [*][256] bf16 row-major.
__device__ __forceinline__
void gemm_mainloop(const unsigned short* __restrict__ A, const unsigned short* __restrict__ B,
                   int m0, int n0, unsigned short* As, unsigned short* Bs,
                   f32x4 (&acc)[4][4], int t)
{
    int lane = t & 63;
    int wv = t >> 6;
    int wr = wv >> 1, wc = wv & 1;
    int r_l = lane & 15;
    int kg_l = lane >> 4;

    for (int kt = 0; kt < 4; ++kt) {
        int c0 = kt * 64;
        #pragma unroll
        for (int i = 0; i < 4; ++i) {
            int idx = t + i * 256;
            int kg = idx & 7, row = idx >> 3;
            int soff = row*64 + ((kg ^ (row & 7)) << 3);
            *reinterpret_cast<short8v*>(&As[soff]) =
                *reinterpret_cast<const short8v*>(&A[(size_t)(m0 + row)*256 + c0 + kg*8]);
            *reinterpret_cast<short8v*>(&Bs[soff]) =
                *reinterpret_cast<const short8v*>(&B[(size_t)(n0 + row)*256 + c0 + kg*8]);
        }
        __syncthreads();
        #pragma unroll
        for (int ks = 0; ks < 2; ++ks) {
            short8v af[4], bfr[4];
            #pragma unroll
            for (int m = 0; m < 4; ++m) {
                int row = wr*64 + m*16 + r_l;
                af[m] = *reinterpret_cast<const short8v*>(
                    &As[row*64 + (((ks*4 + kg_l) ^ (row & 7)) << 3)]);
            }
            #pragma unroll
            for (int n = 0; n < 4; ++n) {
                int row = wc*64 + n*16 + r_l;
                bfr[n] = *reinterpret_cast<const short8v*>(
                    &Bs[row*64 + (((ks*4 + kg_l) ^ (row & 7)) << 3)]);
            }
            #pragma unroll
            for (int m = 0; m < 4; ++m)
                #pragma unroll
                for (int n = 0; n < 4; ++n)
                    acc[m][n] = __builtin_amdgcn_mfma_f32_16x16x32_bf16(af[m], bfr[n], acc[m][n], 0, 0, 0);
        }
        __syncthreads();
    }
}

// ---------------- GEMM1: VO[p][384] = xt @ Wallbf^T + ball ----------------
__global__ __launch_bounds__(256)
void gemm_vo_kernel(const unsigned short* __restrict__ xt, const unsigned short* __restrict__ Wallbf,
                    const float* __restrict__ ball, unsigned short* __restrict__ VO)
{
    __shared__ unsigned short lds[2 * 8192];
    int t = threadIdx.x;
    int m0 = blockIdx.x * 128;   // pixel tile
    int n0 = blockIdx.y * 128;   // output-channel tile
    f32x4 acc[4][4] = {};
    gemm_mainloop(xt, Wallbf, m0, n0, lds, lds + 8192, acc, t);

    int lane = t & 63;
    int wv = t >> 6, wr = wv >> 1, wc = wv & 1;
    int r_l = lane & 15, kg_l = lane >> 4;
    #pragma unroll
    for (int n = 0; n < 4; ++n) {
        int d = n0 + wc*64 + n*16 + r_l;
        float bb = ball[d];
        #pragma unroll
        for (int m = 0; m < 4; ++m) {
            int pr = m0 + wr*64 + m*16 + (kg_l << 2);
            #pragma unroll
            for (int r = 0; r < 4; ++r)
                VO[(size_t)(pr + r)*384 + d] = f2b(acc[m][n][r] + bb);
        }
    }
}

// ---------------- GEMM2 (transposed): out = SiLU(Wout @ y^T + bout), NCHW f32 ----------------
__global__ __launch_bounds__(256)
void gemm_out_kernel(const unsigned short* __restrict__ Woutbf, const unsigned short* __restrict__ y,
                     const float* __restrict__ bout, float* __restrict__ out)
{
    __shared__ unsigned short lds[2 * 8192];
    int t = threadIdx.x;
    int m0 = blockIdx.y * 128;   // d tile (rows of Wout)
    int n0 = blockIdx.x * 128;   // pixel tile
    f32x4 acc[4][4] = {};
    gemm_mainloop(Woutbf, y, m0, n0, lds, lds + 8192, acc, t);

    int lane = t & 63;
    int wv = t >> 6, wr = wv >> 1, wc = wv & 1;
    int r_l = lane & 15, kg_l = lane >> 4;
    int nimg = n0 >> 12;
    int hwb = n0 & 4095;
    #pragma unroll
    for (int m = 0; m < 4; ++m) {
        int dbase = m0 + wr*64 + m*16 + (kg_l << 2);
        #pragma unroll
        for (int r = 0; r < 4; ++r) {
            int d = dbase + r;
            float bb = bout[d];
            #pragma unroll
            for (int n = 0; n < 4; ++n) {
                int pcol = wc*64 + n*16 + r_l;
                float z = acc[m][n][r] + bb;
                float sv = z / (1.f + __expf(-z));
                out[((size_t)(nimg*256 + d))*4096 + hwb + pcol] = sv;
            }
        }
    }
}

// ---------------- DCNv4 core (bf16 in/out) ----------------
__global__ __launch_bounds__(256)
void dcn_kernel(const unsigned short* __restrict__ VO, unsigned short* __restrict__ y)
{
    int p = blockIdx.x;
    int t = threadIdx.x;
    int g = t >> 6, lane = t & 63;
    __shared__ float om_s[108];
    if (t < 108) om_s[t] = b2f(VO[(size_t)p*384 + 256 + t]);
    __syncthreads();

    int hw = p & 4095;
    int h = hw >> 6, w = hw & 63;
    const unsigned short* vbase = VO + (size_t)(p >> 12) * (4096*384) + g*64 + lane;
    const float* o = om_s + g*27;

    float acc = 0.f;
    #pragma unroll
    for (int k = 0; k < 9; ++k) {
        float dxo = o[2*k], dyo = o[2*k+1], m = o[18+k];
        float pxf = (float)(w + (k % 3) - 1) + dxo;
        float pyf = (float)(h + (k / 3) - 1) + dyo;
        float x0f = floorf(pxf), y0f = floorf(pyf);
        float fx = pxf - x0f, fy = pyf - y0f;
        int x0 = (int)x0f, y0 = (int)y0f;
        float s = 0.f;
        #pragma unroll
        for (int dyy = 0; dyy < 2; ++dyy) {
            #pragma unroll
            for (int dxx = 0; dxx < 2; ++dxx) {
                int yy = y0 + dyy, xx = x0 + dxx;
                bool valid = (yy >= 0) & (yy < HH) & (xx >= 0) & (xx < WW);
                float wgt = (dyy ? fy : 1.f - fy) * (dxx ? fx : 1.f - fx);
                int yc = min(max(yy, 0), HH - 1);
                int xc = min(max(xx, 0), WW - 1);
                float v = b2f(vbase[(size_t)(yc * WW + xc) * 384]);
                s = fmaf(v, valid ? wgt : 0.f, s);
            }
        }
        acc = fmaf(m, s, acc);
    }
    y[(size_t)p*256 + g*64 + lane] = f2b(acc);
}

extern "C" void kernel_launch(void* const* d_in, const int* in_sizes, int n_in,
                              void* d_out, int out_size, void* d_ws, size_t ws_size,
                              hipStream_t stream) {
    const float* x       = (const float*)d_in[0];
    const float* cv1_w   = (const float*)d_in[1];
    const float* cv1_b   = (const float*)d_in[2];
    const float* value_w = (const float*)d_in[3];
    const float* value_b = (const float*)d_in[4];
    const float* dw_w    = (const float*)d_in[5];
    const float* dw_b    = (const float*)d_in[6];
    const float* om_w    = (const float*)d_in[7];
    const float* om_b    = (const float*)d_in[8];
    const float* out_w   = (const float*)d_in[9];
    const float* cv2_w   = (const float*)d_in[10];
    const float* bn_g    = (const float*)d_in[11];
    const float* bn_b    = (const float*)d_in[12];
    const float* bn_m    = (const float*)d_in[13];
    const float* bn_v    = (const float*)d_in[14];

    char* ws = (char*)d_ws;
    unsigned short* xt     = (unsigned short*)(ws);
    unsigned short* VO     = (unsigned short*)(ws + 16777216);
    unsigned short* y      = (unsigned short*)(ws + 41943040);
    unsigned short* Wallbf = (unsigned short*)(ws + 58720256);
    unsigned short* Woutbf = (unsigned short*)(ws + 58916864);
    float*          ball   = (float*)(ws + 59047936);
    float*          bout   = (float*)(ws + 59049472);
    float* out = (float*)d_out;

    prep_kernel<<<643, 256, 0, stream>>>(cv1_w, cv1_b, value_w, value_b, dw_w, dw_b,
                                         om_w, om_b, out_w, cv2_w,
                                         bn_g, bn_b, bn_m, bn_v,
                                         Wallbf, ball, Woutbf, bout);
    cvt_tr_kernel<<<dim3(512, 4), 256, 0, stream>>>(x, xt);
    gemm_vo_kernel<<<dim3(256, 3), 256, 0, stream>>>(xt, Wallbf, ball, VO);
    dcn_kernel<<<32768, 256, 0, stream>>>(VO, y);
    gemm_out_kernel<<<dim3(256, 2), 256, 0, stream>>>(Woutbf, y, bout, out);
}

// Round 3
// 95.961 us; speedup vs baseline: 2.8470x; 1.6129x over previous
//
#include <hip/hip_runtime.h>
#include <hip/hip_bf16.h>
#include <math.h>

#define NN    8
#define HH    64
#define WW    64
#define HW    4096
#define NHW   32768
#define DALL  384     // 256 value + 112 om + 16 pad
#define EPSBN 1e-5f

typedef __attribute__((ext_vector_type(8))) short short8v;
typedef __attribute__((ext_vector_type(4))) float f32x4;

__device__ __forceinline__ float b2f(unsigned short u) {
    union { unsigned int i; float f; } v; v.i = ((unsigned int)u) << 16; return v.f;
}
__device__ __forceinline__ unsigned short f2b(float f) {
    __hip_bfloat16 h = __float2bfloat16(f);
    return *reinterpret_cast<const unsigned short*>(&h);
}

// Workspace layout (bytes):
//  xt     [NHW][256] bf16  @ 0          (16777216)
//  VO     [NHW][384] bf16  @ 16777216   (25165824)
//  y      [NHW][256] bf16  @ 41943040   (16777216)
//  Wallbf [384][256] bf16  @ 58720256   (196608)
//  Woutbf [256][256] bf16  @ 58916864   (131072)
//  ball   [384] f32        @ 59047936   (1536)
//  bout   [256] f32        @ 59049472   (1024)

// ---------------- prep: fold weights (f32 math, bf16 weight output) ----------------
__global__ __launch_bounds__(256)
void prep_kernel(const float* __restrict__ cv1_w, const float* __restrict__ cv1_b,
                 const float* __restrict__ value_w, const float* __restrict__ value_b,
                 const float* __restrict__ dw_w, const float* __restrict__ dw_b,
                 const float* __restrict__ om_w, const float* __restrict__ om_b,
                 const float* __restrict__ out_w, const float* __restrict__ cv2_w,
                 const float* __restrict__ bn_g, const float* __restrict__ bn_b,
                 const float* __restrict__ bn_m, const float* __restrict__ bn_v,
                 unsigned short* __restrict__ Wallbf, float* __restrict__ ball,
                 unsigned short* __restrict__ Woutbf, float* __restrict__ bout)
{
    int job = blockIdx.x * 256 + threadIdx.x;
    if (job < 65536) {                          // Wv = value_w @ cv1_w
        int d = job >> 8, cc = job & 255;
        float s = 0.f;
        for (int e = 0; e < 256; ++e)
            s = fmaf(value_w[d*256+e], cv1_w[e*256+cc], s);
        Wallbf[job] = f2b(s);
    } else if (job < 94208) {                   // Wom = om_w.diag(dw_w) @ cv1_w
        int idx = job - 65536;
        int o = idx >> 8, cc = idx & 255;
        float s = 0.f;
        for (int e = 0; e < 256; ++e)
            s = fmaf(om_w[o*256+e]*dw_w[e], cv1_w[e*256+cc], s);
        Wallbf[job] = f2b(s);
    } else if (job < 98304) {                   // pad rows 368..383
        Wallbf[job] = 0;
    } else if (job < 163840) {                  // Wout = diag(s) cv2_w @ out_w
        int idx = job - 98304;
        int d = idx >> 8;
        float s = 0.f;
        for (int e = 0; e < 256; ++e)
            s = fmaf(cv2_w[d*256+e], out_w[e*256 + (idx & 255)], s);
        float sc = bn_g[d] * rsqrtf(bn_v[d] + EPSBN);
        Woutbf[idx] = f2b(s * sc);
    } else if (job < 164096) {                  // bv
        int d = job - 163840;
        float s = value_b[d];
        for (int e = 0; e < 256; ++e) s = fmaf(value_w[d*256+e], cv1_b[e], s);
        ball[d] = s;
    } else if (job < 164208) {                  // bom
        int o = job - 164096;
        float s = om_b[o];
        for (int e = 0; e < 256; ++e)
            s = fmaf(om_w[o*256+e], fmaf(dw_w[e], cv1_b[e], dw_b[e]), s);
        ball[256 + o] = s;
    } else if (job < 164224) {                  // ball pad
        ball[368 + job - 164208] = 0.f;
    } else if (job < 164480) {                  // bout
        int d = job - 164224;
        float sc = bn_g[d] * rsqrtf(bn_v[d] + EPSBN);
        bout[d] = fmaf(-bn_m[d], sc, bn_b[d]);
    }
}

// ---------------- cvt+transpose: x NCHW f32 -> xt [p][c] bf16 ----------------
__global__ __launch_bounds__(256)
void cvt_tr_kernel(const float* __restrict__ x, unsigned short* __restrict__ xt)
{
    __shared__ float Ls[64][65];
    int p0 = blockIdx.x * 64;
    int c0 = blockIdx.y * 64;
    int n = p0 >> 12, hw0 = p0 & 4095;
    int t = threadIdx.x;
    #pragma unroll
    for (int i = 0; i < 16; ++i) {
        int idx = t + i * 256;
        int cc = idx >> 6, pp = idx & 63;
        Ls[cc][pp] = x[((size_t)(n*256 + c0 + cc))*4096 + hw0 + pp];
    }
    __syncthreads();
    #pragma unroll
    for (int i = 0; i < 8; ++i) {
        int idx = t + i * 256;
        int pp = idx >> 5, cp = idx & 31;
        int c = cp * 2;
        ushort2 v;
        v.x = f2b(Ls[c][pp]);
        v.y = f2b(Ls[c+1][pp]);
        *reinterpret_cast<ushort2*>(&xt[(size_t)(p0 + pp)*256 + c0 + c]) = v;
    }
}

// ---------------- shared MFMA mainloop: 128x128 tile, BK=64, K=256 ----------------
__device__ __forceinline__
void gemm_mainloop(const unsigned short* __restrict__ A, const unsigned short* __restrict__ B,
                   int m0, int n0, unsigned short* As, unsigned short* Bs,
                   f32x4 (&acc)[4][4], int t)
{
    int lane = t & 63;
    int wv = t >> 6;
    int wr = wv >> 1, wc = wv & 1;
    int r_l = lane & 15;
    int kg_l = lane >> 4;

    for (int kt = 0; kt < 4; ++kt) {
        int c0 = kt * 64;
        #pragma unroll
        for (int i = 0; i < 4; ++i) {
            int idx = t + i * 256;
            int kg = idx & 7, row = idx >> 3;
            int soff = row*64 + ((kg ^ (row & 7)) << 3);
            *reinterpret_cast<short8v*>(&As[soff]) =
                *reinterpret_cast<const short8v*>(&A[(size_t)(m0 + row)*256 + c0 + kg*8]);
            *reinterpret_cast<short8v*>(&Bs[soff]) =
                *reinterpret_cast<const short8v*>(&B[(size_t)(n0 + row)*256 + c0 + kg*8]);
        }
        __syncthreads();
        #pragma unroll
        for (int ks = 0; ks < 2; ++ks) {
            short8v af[4], bfr[4];
            #pragma unroll
            for (int m = 0; m < 4; ++m) {
                int row = wr*64 + m*16 + r_l;
                af[m] = *reinterpret_cast<const short8v*>(
                    &As[row*64 + (((ks*4 + kg_l) ^ (row & 7)) << 3)]);
            }
            #pragma unroll
            for (int n = 0; n < 4; ++n) {
                int row = wc*64 + n*16 + r_l;
                bfr[n] = *reinterpret_cast<const short8v*>(
                    &Bs[row*64 + (((ks*4 + kg_l) ^ (row & 7)) << 3)]);
            }
            #pragma unroll
            for (int m = 0; m < 4; ++m)
                #pragma unroll
                for (int n = 0; n < 4; ++n)
                    acc[m][n] = __builtin_amdgcn_mfma_f32_16x16x32_bf16(af[m], bfr[n], acc[m][n], 0, 0, 0);
        }
        __syncthreads();
    }
}

// ---------------- GEMM1: VO[p][384] = xt @ Wallbf^T + ball ----------------
__global__ __launch_bounds__(256)
void gemm_vo_kernel(const unsigned short* __restrict__ xt, const unsigned short* __restrict__ Wallbf,
                    const float* __restrict__ ball, unsigned short* __restrict__ VO)
{
    __shared__ unsigned short lds[2 * 8192];
    int t = threadIdx.x;
    int m0 = blockIdx.x * 128;   // pixel tile
    int n0 = blockIdx.y * 128;   // output-channel tile
    f32x4 acc[4][4] = {};
    gemm_mainloop(xt, Wallbf, m0, n0, lds, lds + 8192, acc, t);

    int lane = t & 63;
    int wv = t >> 6, wr = wv >> 1, wc = wv & 1;
    int r_l = lane & 15, kg_l = lane >> 4;
    #pragma unroll
    for (int n = 0; n < 4; ++n) {
        int d = n0 + wc*64 + n*16 + r_l;
        float bb = ball[d];
        #pragma unroll
        for (int m = 0; m < 4; ++m) {
            int pr = m0 + wr*64 + m*16 + (kg_l << 2);
            #pragma unroll
            for (int r = 0; r < 4; ++r)
                VO[(size_t)(pr + r)*384 + d] = f2b(acc[m][n][r] + bb);
        }
    }
}

// ---------------- GEMM2 (transposed): out = SiLU(Wout @ y^T + bout), NCHW f32 ----------------
__global__ __launch_bounds__(256)
void gemm_out_kernel(const unsigned short* __restrict__ Woutbf, const unsigned short* __restrict__ y,
                     const float* __restrict__ bout, float* __restrict__ out)
{
    __shared__ unsigned short lds[2 * 8192];
    int t = threadIdx.x;
    int m0 = blockIdx.y * 128;   // d tile (rows of Wout)
    int n0 = blockIdx.x * 128;   // pixel tile
    f32x4 acc[4][4] = {};
    gemm_mainloop(Woutbf, y, m0, n0, lds, lds + 8192, acc, t);

    int lane = t & 63;
    int wv = t >> 6, wr = wv >> 1, wc = wv & 1;
    int r_l = lane & 15, kg_l = lane >> 4;
    int nimg = n0 >> 12;
    int hwb = n0 & 4095;
    #pragma unroll
    for (int m = 0; m < 4; ++m) {
        int dbase = m0 + wr*64 + m*16 + (kg_l << 2);
        #pragma unroll
        for (int r = 0; r < 4; ++r) {
            int d = dbase + r;
            float bb = bout[d];
            #pragma unroll
            for (int n = 0; n < 4; ++n) {
                int pcol = wc*64 + n*16 + r_l;
                float z = acc[m][n][r] + bb;
                float sv = z / (1.f + __expf(-z));
                out[((size_t)(nimg*256 + d))*4096 + hwb + pcol] = sv;
            }
        }
    }
}

// ---------------- DCNv4 core: 8 channels/lane, 8 px x 4 grp x 8 lanes per block ----------------
__global__ __launch_bounds__(256)
void dcn_kernel(const unsigned short* __restrict__ VO, unsigned short* __restrict__ y)
{
    __shared__ float om_s[8][108];
    int t = threadIdx.x;
    int p0 = blockIdx.x * 8;

    for (int i = t; i < 864; i += 256) {
        int pl = i / 108, j = i - pl * 108;
        om_s[pl][j] = b2f(VO[(size_t)(p0 + pl)*384 + 256 + j]);
    }
    __syncthreads();

    int slot = t >> 3, ch8 = t & 7;
    int pl = slot >> 2, g = slot & 3;
    int p = p0 + pl;
    int hw = p & 4095;
    int h = hw >> 6, w = hw & 63;
    const unsigned short* vbase = VO + (size_t)(p >> 12) * (HW * (size_t)DALL) + g*64 + ch8*8;
    const float* o = &om_s[pl][g*27];

    float acc[8] = {};
    #pragma unroll
    for (int k = 0; k < 9; ++k) {
        float dxo = o[2*k], dyo = o[2*k+1], m = o[18+k];
        float pxf = (float)(w + (k % 3) - 1) + dxo;
        float pyf = (float)(h + (k / 3) - 1) + dyo;
        float x0f = floorf(pxf), y0f = floorf(pyf);
        float fx = pxf - x0f, fy = pyf - y0f;
        int x0 = (int)x0f, y0 = (int)y0f;
        #pragma unroll
        for (int dyy = 0; dyy < 2; ++dyy) {
            #pragma unroll
            for (int dxx = 0; dxx < 2; ++dxx) {
                int yy = y0 + dyy, xx = x0 + dxx;
                bool valid = (yy >= 0) & (yy < HH) & (xx >= 0) & (xx < WW);
                float wgt = (dyy ? fy : 1.f - fy) * (dxx ? fx : 1.f - fx);
                float wm = valid ? (m * wgt) : 0.f;
                int yc = min(max(yy, 0), HH - 1);
                int xc = min(max(xx, 0), WW - 1);
                short8v v = *reinterpret_cast<const short8v*>(
                    &vbase[(size_t)(yc * WW + xc) * DALL]);
                #pragma unroll
                for (int c = 0; c < 8; ++c)
                    acc[c] = fmaf(b2f((unsigned short)v[c]), wm, acc[c]);
            }
        }
    }
    short8v ov;
    #pragma unroll
    for (int c = 0; c < 8; ++c) ov[c] = (short)f2b(acc[c]);
    *reinterpret_cast<short8v*>(&y[(size_t)p*256 + g*64 + ch8*8]) = ov;
}

extern "C" void kernel_launch(void* const* d_in, const int* in_sizes, int n_in,
                              void* d_out, int out_size, void* d_ws, size_t ws_size,
                              hipStream_t stream) {
    const float* x       = (const float*)d_in[0];
    const float* cv1_w   = (const float*)d_in[1];
    const float* cv1_b   = (const float*)d_in[2];
    const float* value_w = (const float*)d_in[3];
    const float* value_b = (const float*)d_in[4];
    const float* dw_w    = (const float*)d_in[5];
    const float* dw_b    = (const float*)d_in[6];
    const float* om_w    = (const float*)d_in[7];
    const float* om_b    = (const float*)d_in[8];
    const float* out_w   = (const float*)d_in[9];
    const float* cv2_w   = (const float*)d_in[10];
    const float* bn_g    = (const float*)d_in[11];
    const float* bn_b    = (const float*)d_in[12];
    const float* bn_m    = (const float*)d_in[13];
    const float* bn_v    = (const float*)d_in[14];

    char* ws = (char*)d_ws;
    unsigned short* xt     = (unsigned short*)(ws);
    unsigned short* VO     = (unsigned short*)(ws + 16777216);
    unsigned short* y      = (unsigned short*)(ws + 41943040);
    unsigned short* Wallbf = (unsigned short*)(ws + 58720256);
    unsigned short* Woutbf = (unsigned short*)(ws + 58916864);
    float*          ball   = (float*)(ws + 59047936);
    float*          bout   = (float*)(ws + 59049472);
    float* out = (float*)d_out;

    prep_kernel<<<643, 256, 0, stream>>>(cv1_w, cv1_b, value_w, value_b, dw_w, dw_b,
                                         om_w, om_b, out_w, cv2_w,
                                         bn_g, bn_b, bn_m, bn_v,
                                         Wallbf, ball, Woutbf, bout);
    cvt_tr_kernel<<<dim3(512, 4), 256, 0, stream>>>(x, xt);
    gemm_vo_kernel<<<dim3(256, 3), 256, 0, stream>>>(xt, Wallbf, ball, VO);
    dcn_kernel<<<4096, 256, 0, stream>>>(VO, y);
    gemm_out_kernel<<<dim3(256, 2), 256, 0, stream>>>(Woutbf, y, bout, out);
}